// Round 1
// baseline (117.456 us; speedup 1.0000x reference)
//
#include <hip/hip_runtime.h>
#include <math.h>

// Third-order scattering via double-Parseval:
//   out[b,i,j] = (1/MN^2) * sum_n xa_{b,i}[n] * d_{b,j}[n]
// xa_i = abs_eps(inv2(F_i * X)/MN), d_j = Re(inv2_un(F_j^2 * X)), X = fft2(x).
// X in NATURAL frequency layout; inverse FFTs are conjugate-DIF (same DIF
// dataflow as forward, conjugated twiddles): natural freq input ->
// bit-reversed spatial output. Both fields share the permutation, so the
// spatial dot products are unaffected.
//
// Hard-won constraints:
//  - R7: cooperative single-kernel fusion regressed 2.8x (grid.sync spin +
//    VGPR-52 spill). Do not fuse.
//  - R8/R9: the inverse FFT MUST be the conjugate-DIF (span-64 stage FIRST,
//    h=32..1, forward-butterfly form, conjugated twiddles). A DIT-style
//    mirrored inverse expects bit-reversed input and silently breaks.
//  - R10: k_dot float4+XCD-affine restructure coincided with +9us total and
//    a 137us cold-dispatch stall; reverted to the R6 body (115.8us best).
//  - R11 (this round): branchless butterfly. The divergent if/else stage body
//    if-converts to ~10 VALU/(value,stage); replaced with uniform
//    q = fma(sgn,a,p); a' = q*e  where sgn/e are per-lane constants hoisted
//    into make_tw (e=(1,0) on lo lanes). 6 VALU/(value,stage), same DS ops,
//    mathematically identical per lane. k_prep/k_fields are per-CU
//    VALU-issue-bound (130 blocks < 256 CUs => wall time = per-block time).
//
// 3 dispatches:
//  k_prep   : blocks 0,1: X_b = fft2(x_b); block 2: zero out.
//  k_fields : 130 fat blocks: 66 d-fields + 64 xa-fields.
//  k_dot    : 256 blocks = (b,i) x 4 k-slices; register acc[33], shfl reduce.

#define PI_F 3.14159265358979323846f

// Per-lane stage constants: effective twiddle e[s] = hi ? W : (1,0),
// sign sg[s] = hi ? -1 : +1, plus the span-64 head twiddle hw.
__device__ __forceinline__ void make_tw(int lane, float* er, float* ei,
                                        float* sg, float* hw) {
#pragma unroll
  for (int s = 0; s < 6; ++s) {
    int h = 32 >> s;
    bool hi = (lane & h) != 0;
    float ang = -PI_F * (float)(lane & (h - 1)) / (float)h;
    float sv, cv;
    __sincosf(ang, &sv, &cv);
    er[s] = hi ? cv : 1.0f;
    ei[s] = hi ? sv : 0.0f;
    sg[s] = hi ? -1.0f : 1.0f;
  }
  float ang = -PI_F * (float)lane / 64.0f;
  float sv, cv;
  __sincosf(ang, &sv, &cv);
  hw[0] = cv; hw[1] = sv;
}

// DIF radix-2: natural-order input (lane t holds x[t], x[t+64]); output slot s
// holds X[brev7(s)]. S=+1: forward (W^-); S=-1: inverse, unnormalized (W^+),
// SAME dataflow with conjugated twiddles (conjugate-DIF). [R6/R7/R10-proven]
// Branchless stage body [R11]: lo lanes get sgn=+1, e=(1,0) -> a' = a + p;
// hi lanes get sgn=-1, e=W -> a' = (p - a)*W. Identical to the divergent form.
template <int S>
__device__ __forceinline__ void fft128_dif(float& ar, float& ai, float& br, float& bi,
                                           const float* er, const float* ei,
                                           const float* sg, const float* hw) {
  float s6r = hw[0], s6i = (S > 0) ? hw[1] : -hw[1];
  float ur = ar + br, ui = ai + bi;
  float vr = ar - br, vi = ai - bi;
  ar = ur; ai = ui;
  br = vr * s6r - vi * s6i;
  bi = vr * s6i + vi * s6r;
#pragma unroll
  for (int s = 0; s < 6; ++s) {
    int h = 32 >> s;
    float wr = er[s], wi = (S > 0) ? ei[s] : -ei[s], sn = sg[s];
    float pr, pi2, qr, qi;
    pr = __shfl_xor(ar, h, 64); pi2 = __shfl_xor(ai, h, 64);
    qr = fmaf(sn, ar, pr); qi = fmaf(sn, ai, pi2);
    ar = qr * wr - qi * wi;
    ai = qr * wi + qi * wr;
    pr = __shfl_xor(br, h, 64); pi2 = __shfl_xor(bi, h, 64);
    qr = fmaf(sn, br, pr); qi = fmaf(sn, bi, pi2);
    br = qr * wr - qi * wi;
    bi = qr * wi + qi * wr;
  }
}

// rows (row r=8w+t, slots c=lane/lane+64) -> cols (col c=8w+ci, slots r=lane/lane+64)
// via 64KB tile in two 64-row chunks; XOR swizzle (c ^ (r&15)) => conflict-free.
__device__ __forceinline__ void transpose_r2c(float (&dr)[16], float (&di)[16],
    float (&er)[8], float (&ei)[8], float (&fr)[8], float (&fi2)[8],
    float2 (*tile)[128], int lane, int w) {
#pragma unroll
  for (int ch = 0; ch < 2; ++ch) {
    if ((w >> 3) == ch) {
#pragma unroll
      for (int t = 0; t < 8; ++t) {
        int r = w * 8 + t;
        int rr = r & 63, sw = r & 15;
        tile[rr][lane ^ sw] = make_float2(dr[2 * t], di[2 * t]);
        tile[rr][(lane + 64) ^ sw] = make_float2(dr[2 * t + 1], di[2 * t + 1]);
      }
    }
    __syncthreads();
    {
      int sw = lane & 15;
#pragma unroll
      for (int ci = 0; ci < 8; ++ci) {
        int c = w * 8 + ci;
        float2 v = tile[lane][c ^ sw];
        if (ch == 0) { er[ci] = v.x; ei[ci] = v.y; }
        else { fr[ci] = v.x; fi2[ci] = v.y; }
      }
    }
    __syncthreads();
  }
}

// blocks 0,1: X[b] = fft2(x[b]), stored in NATURAL (u,v) frequency layout.
// block 2: zero out[1344].
__global__ __launch_bounds__(1024, 2) void k_prep(const float* __restrict__ x,
    float2* __restrict__ X, float* __restrict__ out) {
  __shared__ float2 tile[64][128];
  int tid = threadIdx.x;
  if (blockIdx.x == 2) {
    if (tid < 1344) out[tid] = 0.f;
    if (tid < 320) out[tid + 1024] = 0.f;
    return;
  }
  int b = blockIdx.x;
  int lane = tid & 63, w = tid >> 6;
  float twer[6], twei[6], twsg[6], twh[2];
  make_tw(lane, twer, twei, twsg, twh);
  const float* xb = x + b * 16384;
  float dr[16], di[16];
  float er[8], ei[8], fr[8], fi2[8];
#pragma unroll
  for (int t = 0; t < 8; ++t) {  // rows u = 8w+t: fwd v-FFT (real input)
    int r = w * 8 + t;
    float ar = xb[r * 128 + lane], ai2 = 0.f, br = xb[r * 128 + lane + 64], bi = 0.f;
    fft128_dif<1>(ar, ai2, br, bi, twer, twei, twsg, twh);
    dr[2 * t] = ar; di[2 * t] = ai2; dr[2 * t + 1] = br; di[2 * t + 1] = bi;
  }
  transpose_r2c(dr, di, er, ei, fr, fi2, tile, lane, w);
  int u0 = __brev((unsigned)lane) >> 25;  // brev7(lane); brev7(lane+64)=u0+1
#pragma unroll
  for (int ci = 0; ci < 8; ++ci) {  // cols: fwd u-FFT, brev scatter-store
    int c = w * 8 + ci;
    float ar = er[ci], ai2 = ei[ci], br = fr[ci], bi = fi2[ci];
    fft128_dif<1>(ar, ai2, br, bi, twer, twei, twsg, twh);
    int vn = __brev((unsigned)c) >> 25;
    X[b * 16384 + u0 * 128 + vn] = make_float2(ar, ai2);
    X[b * 16384 + (u0 + 1) * 128 + vn] = make_float2(br, bi);
  }
}

// blocks 0..65:  (b,j): d  = Re(inv2_un(F_j^2 * X_b))          -> dfld[b*33+j]
// blocks 66..129:(b,i): xa = abs_eps(inv2_un(F_i * X_b)/MN)    -> xa[b*32+i]
// Fields stored in (sigma_sv col, sigma_su row) layout -- consistent for both.
__global__ __launch_bounds__(1024, 2) void k_fields(const float2* __restrict__ X,
    const float* __restrict__ F, float* __restrict__ dfld, float* __restrict__ xa) {
  __shared__ float2 tile[64][128];
  int tid = threadIdx.x, lane = tid & 63, w = tid >> 6;
  bool isd = (blockIdx.x < 66);
  int b, f;
  float* optr;
  if (isd) {
    b = blockIdx.x / 33; f = blockIdx.x - b * 33;
    optr = dfld + blockIdx.x * 16384;
  } else {
    int q = blockIdx.x - 66; b = q >> 5; f = q & 31;
    optr = xa + q * 16384;
  }
  const float* Fb = F + f * 16384;
  float twer[6], twei[6], twsg[6], twh[2];
  make_tw(lane, twer, twei, twsg, twh);
  const float2* Xb = X + b * 16384;
  float dr[16], di[16];
  float er[8], ei[8], fr[8], fi2[8];

  // P1: rows u (natural): Y = F (or F^2) * X, inverse v-FFT (natural -> sigma_sv)
#pragma unroll
  for (int t = 0; t < 8; ++t) {
    int r = w * 8 + t;
    float2 x0 = Xb[r * 128 + lane];
    float2 x1 = Xb[r * 128 + lane + 64];
    float f0 = Fb[r * 128 + lane], f1 = Fb[r * 128 + lane + 64];
    if (isd) { f0 *= f0; f1 *= f1; }
    float ar = x0.x * f0, ai2 = x0.y * f0, br = x1.x * f1, bi = x1.y * f1;
    fft128_dif<-1>(ar, ai2, br, bi, twer, twei, twsg, twh);
    dr[2 * t] = ar; di[2 * t] = ai2; dr[2 * t + 1] = br; di[2 * t + 1] = bi;
  }
  transpose_r2c(dr, di, er, ei, fr, fi2, tile, lane, w);

  // P2: per col sigma_sv: inverse u-FFT (natural -> sigma_su), store Re / abs_eps.
  const float sc = 1.0f / 16384.0f;
#pragma unroll
  for (int ci = 0; ci < 8; ++ci) {
    int c = w * 8 + ci;
    float ar = er[ci], ai2 = ei[ci], br = fr[ci], bi = fi2[ci];
    fft128_dif<-1>(ar, ai2, br, bi, twer, twei, twsg, twh);
    if (isd) {
      optr[c * 128 + lane] = ar;
      optr[c * 128 + lane + 64] = br;
    } else {
      float t0r = ar * sc, t0i = ai2 * sc, t1r = br * sc, t1i = bi * sc;
      optr[c * 128 + lane] = sqrtf(t0r * t0r + t0i * t0i + 1e-6f);
      optr[c * 128 + lane + 64] = sqrtf(t1r * t1r + t1i * t1i + 1e-6f);
    }
  }
}

// [R6-proven body] 256 blocks = (b,i)[64] x k-slice[4]; 512 threads; register
// acc[33]; wave shfl-reduce -> LDS[8][33] -> 33 atomicAdds per block.
__global__ __launch_bounds__(512) void k_dot(const float* __restrict__ xa,
    const float* __restrict__ dfld, float* __restrict__ out) {
  int im = blockIdx.x >> 2;        // 0..63  (b*32+i)
  int slice = blockIdx.x & 3;
  int b = im >> 5, i = im & 31;
  int t = threadIdx.x;             // 0..511
  const float* xr = xa + im * 16384 + slice * 4096;
  const float* db = dfld + b * 33 * 16384 + slice * 4096;
  float acc[33];
#pragma unroll
  for (int j = 0; j < 33; ++j) acc[j] = 0.f;
#pragma unroll
  for (int it = 0; it < 8; ++it) {
    int k = it * 512 + t;
    float xv = xr[k];
#pragma unroll
    for (int j = 0; j < 33; ++j) acc[j] += xv * db[j * 16384 + k];
  }
  // wave-level reduction per j
#pragma unroll
  for (int j = 0; j < 33; ++j) {
#pragma unroll
    for (int off = 32; off > 0; off >>= 1) acc[j] += __shfl_xor(acc[j], off, 64);
  }
  __shared__ float red[8][33];
  int w = t >> 6, lane = t & 63;
  if (lane == 0) {
#pragma unroll
    for (int j = 0; j < 33; ++j) red[w][j] = acc[j];
  }
  __syncthreads();
  if (t < 33) {
    float s = 0.f;
#pragma unroll
    for (int w2 = 0; w2 < 8; ++w2) s += red[w2][t];
    // decode output position for (i, j=t)
    int j = t;
    int j1 = i >> 3, l1 = i & 7;
    const int pref[4] = {0, 264, 464, 600};
    int per = (4 - j1) * 8 + 1;
    int start = pref[j1] + l1 * per;
    int pos = -1;
    if (j == 32) pos = start + per - 1;
    else {
      int j2 = j >> 3;
      if (j2 >= j1) pos = start + (j2 - j1) * 8 + (j & 7);
    }
    if (pos >= 0)
      atomicAdd(out + b * 672 + pos, s * (1.0f / 16384.0f) * (1.0f / 16384.0f));
  }
}

extern "C" void kernel_launch(void* const* d_in, const int* in_sizes, int n_in,
                              void* d_out, int out_size, void* d_ws, size_t ws_size,
                              hipStream_t stream) {
  (void)in_sizes; (void)n_in; (void)out_size; (void)ws_size;
  const float* x = (const float*)d_in[0];   // (2,1,128,128)
  const float* F = (const float*)d_in[1];   // (1,33,128,128)
  float* out = (float*)d_out;               // (2,672)
  char* ws = (char*)d_ws;
  // ws: X @0 (262144 B) | dfld @262144 (4325376 B) | xa @4587520 (4194304 B)
  float2* X = (float2*)(ws + 0);
  float* dfld = (float*)(ws + 262144);
  float* xa = (float*)(ws + 4587520);

  hipLaunchKernelGGL(k_prep, dim3(3), dim3(1024), 0, stream, x, X, out);
  hipLaunchKernelGGL(k_fields, dim3(130), dim3(1024), 0, stream, X, F, dfld, xa);
  hipLaunchKernelGGL(k_dot, dim3(256), dim3(512), 0, stream, xa, dfld, out);
}

// Round 2
// 113.727 us; speedup vs baseline: 1.0328x; 1.0328x over previous
//
#include <hip/hip_runtime.h>
#include <math.h>

// Third-order scattering via double-Parseval:
//   out[b,i,j] = (1/MN^2) * sum_n xa_{b,i}[n] * d_{b,j}[n]
// xa_i = abs_eps(inv2(F_i * X)/MN), d_j = Re(inv2_un(F_j^2 * X)), X = fft2(x).
// X in NATURAL frequency layout; inverse FFTs are conjugate-DIF (same DIF
// dataflow as forward, conjugated twiddles): natural freq input ->
// bit-reversed spatial output. Both fields share the permutation, so the
// spatial dot products are unaffected.
//
// Hard-won constraints:
//  - R7: cooperative single-kernel fusion regressed 2.8x (grid.sync spin +
//    VGPR-52 spill). Do not fuse.
//  - R8/R9: the inverse FFT MUST be the conjugate-DIF (span-64 stage FIRST,
//    h=32..1, forward-butterfly form, conjugated twiddles). A DIT-style
//    mirrored inverse expects bit-reversed input and silently breaks.
//  - R10: k_dot float4+XCD-affine restructure coincided with +9us total and
//    a 137us cold-dispatch stall; reverted to the R6 body (115.8us best).
//  - R11 FAILED (+2.9us): branchless fma-butterfly regressed vs the divergent
//    if/else form. Compiler's if-conversion of the divergent body is already
//    near-optimal; the uniform form serializes shfl->fma->cmul and carries
//    +6 VGPRs of lane constants. KEEP the divergent R6 butterfly.
//  - R12 (this round): k_dot float4 loads ONLY (no XCD-affine, no other
//    change). k_dot is VMEM-issue-bound: 272 scalar loads vs 264 FMAs per
//    thread. float4 cuts load instructions to 68 at identical traffic.
//
// 3 dispatches:
//  k_prep   : blocks 0,1: X_b = fft2(x_b); block 2: zero out.
//  k_fields : 130 fat blocks: 66 d-fields + 64 xa-fields.
//  k_dot    : 256 blocks = (b,i) x 4 k-slices; register acc[33], shfl reduce.

#define PI_F 3.14159265358979323846f

__device__ __forceinline__ void make_tw(int lane, float* twr, float* twi) {
#pragma unroll
  for (int s = 0; s < 6; ++s) {
    int h = 32 >> s;
    float ang = -PI_F * (float)(lane & (h - 1)) / (float)h;
    float sv, cv;
    __sincosf(ang, &sv, &cv);
    twr[s] = cv; twi[s] = sv;
  }
  float ang = -PI_F * (float)lane / 64.0f;
  float sv, cv;
  __sincosf(ang, &sv, &cv);
  twr[6] = cv; twi[6] = sv;
}

// DIF radix-2: natural-order input (lane t holds x[t], x[t+64]); output slot s
// holds X[brev7(s)]. S=+1: forward (W^-); S=-1: inverse, unnormalized (W^+),
// SAME dataflow with conjugated twiddles (conjugate-DIF). [R6/R7/R10-proven]
template <int S>
__device__ __forceinline__ void fft128_dif(float& ar, float& ai, float& br, float& bi,
                                           const float* twr, const float* twi, int lane) {
  float s6r = twr[6], s6i = (S > 0) ? twi[6] : -twi[6];
  float ur = ar + br, ui = ai + bi;
  float vr = ar - br, vi = ai - bi;
  ar = ur; ai = ui;
  br = vr * s6r - vi * s6i;
  bi = vr * s6i + vi * s6r;
#pragma unroll
  for (int s = 0; s < 6; ++s) {
    int h = 32 >> s;
    float wr = twr[s], wi = (S > 0) ? twi[s] : -twi[s];
    bool hi = (lane & h) != 0;
    float pr, pi2;
    pr = __shfl_xor(ar, h, 64); pi2 = __shfl_xor(ai, h, 64);
    if (!hi) { ar += pr; ai += pi2; }
    else { float dr = pr - ar, di = pi2 - ai; ar = dr * wr - di * wi; ai = dr * wi + di * wr; }
    pr = __shfl_xor(br, h, 64); pi2 = __shfl_xor(bi, h, 64);
    if (!hi) { br += pr; bi += pi2; }
    else { float dr = pr - br, di = pi2 - bi; br = dr * wr - di * wi; bi = dr * wi + di * wr; }
  }
}

// rows (row r=8w+t, slots c=lane/lane+64) -> cols (col c=8w+ci, slots r=lane/lane+64)
// via 64KB tile in two 64-row chunks; XOR swizzle (c ^ (r&15)) => conflict-free.
__device__ __forceinline__ void transpose_r2c(float (&dr)[16], float (&di)[16],
    float (&er)[8], float (&ei)[8], float (&fr)[8], float (&fi2)[8],
    float2 (*tile)[128], int lane, int w) {
#pragma unroll
  for (int ch = 0; ch < 2; ++ch) {
    if ((w >> 3) == ch) {
#pragma unroll
      for (int t = 0; t < 8; ++t) {
        int r = w * 8 + t;
        int rr = r & 63, sw = r & 15;
        tile[rr][lane ^ sw] = make_float2(dr[2 * t], di[2 * t]);
        tile[rr][(lane + 64) ^ sw] = make_float2(dr[2 * t + 1], di[2 * t + 1]);
      }
    }
    __syncthreads();
    {
      int sw = lane & 15;
#pragma unroll
      for (int ci = 0; ci < 8; ++ci) {
        int c = w * 8 + ci;
        float2 v = tile[lane][c ^ sw];
        if (ch == 0) { er[ci] = v.x; ei[ci] = v.y; }
        else { fr[ci] = v.x; fi2[ci] = v.y; }
      }
    }
    __syncthreads();
  }
}

// blocks 0,1: X[b] = fft2(x[b]), stored in NATURAL (u,v) frequency layout.
// block 2: zero out[1344].
__global__ __launch_bounds__(1024, 2) void k_prep(const float* __restrict__ x,
    float2* __restrict__ X, float* __restrict__ out) {
  __shared__ float2 tile[64][128];
  int tid = threadIdx.x;
  if (blockIdx.x == 2) {
    if (tid < 1344) out[tid] = 0.f;
    if (tid < 320) out[tid + 1024] = 0.f;
    return;
  }
  int b = blockIdx.x;
  int lane = tid & 63, w = tid >> 6;
  float twr[7], twi[7]; make_tw(lane, twr, twi);
  const float* xb = x + b * 16384;
  float dr[16], di[16];
  float er[8], ei[8], fr[8], fi2[8];
#pragma unroll
  for (int t = 0; t < 8; ++t) {  // rows u = 8w+t: fwd v-FFT (real input)
    int r = w * 8 + t;
    float ar = xb[r * 128 + lane], ai2 = 0.f, br = xb[r * 128 + lane + 64], bi = 0.f;
    fft128_dif<1>(ar, ai2, br, bi, twr, twi, lane);
    dr[2 * t] = ar; di[2 * t] = ai2; dr[2 * t + 1] = br; di[2 * t + 1] = bi;
  }
  transpose_r2c(dr, di, er, ei, fr, fi2, tile, lane, w);
  int u0 = __brev((unsigned)lane) >> 25;  // brev7(lane); brev7(lane+64)=u0+1
#pragma unroll
  for (int ci = 0; ci < 8; ++ci) {  // cols: fwd u-FFT, brev scatter-store
    int c = w * 8 + ci;
    float ar = er[ci], ai2 = ei[ci], br = fr[ci], bi = fi2[ci];
    fft128_dif<1>(ar, ai2, br, bi, twr, twi, lane);
    int vn = __brev((unsigned)c) >> 25;
    X[b * 16384 + u0 * 128 + vn] = make_float2(ar, ai2);
    X[b * 16384 + (u0 + 1) * 128 + vn] = make_float2(br, bi);
  }
}

// blocks 0..65:  (b,j): d  = Re(inv2_un(F_j^2 * X_b))          -> dfld[b*33+j]
// blocks 66..129:(b,i): xa = abs_eps(inv2_un(F_i * X_b)/MN)    -> xa[b*32+i]
// Fields stored in (sigma_sv col, sigma_su row) layout -- consistent for both.
__global__ __launch_bounds__(1024, 2) void k_fields(const float2* __restrict__ X,
    const float* __restrict__ F, float* __restrict__ dfld, float* __restrict__ xa) {
  __shared__ float2 tile[64][128];
  int tid = threadIdx.x, lane = tid & 63, w = tid >> 6;
  bool isd = (blockIdx.x < 66);
  int b, f;
  float* optr;
  if (isd) {
    b = blockIdx.x / 33; f = blockIdx.x - b * 33;
    optr = dfld + blockIdx.x * 16384;
  } else {
    int q = blockIdx.x - 66; b = q >> 5; f = q & 31;
    optr = xa + q * 16384;
  }
  const float* Fb = F + f * 16384;
  float twr[7], twi[7]; make_tw(lane, twr, twi);
  const float2* Xb = X + b * 16384;
  float dr[16], di[16];
  float er[8], ei[8], fr[8], fi2[8];

  // P1: rows u (natural): Y = F (or F^2) * X, inverse v-FFT (natural -> sigma_sv)
#pragma unroll
  for (int t = 0; t < 8; ++t) {
    int r = w * 8 + t;
    float2 x0 = Xb[r * 128 + lane];
    float2 x1 = Xb[r * 128 + lane + 64];
    float f0 = Fb[r * 128 + lane], f1 = Fb[r * 128 + lane + 64];
    if (isd) { f0 *= f0; f1 *= f1; }
    float ar = x0.x * f0, ai2 = x0.y * f0, br = x1.x * f1, bi = x1.y * f1;
    fft128_dif<-1>(ar, ai2, br, bi, twr, twi, lane);
    dr[2 * t] = ar; di[2 * t] = ai2; dr[2 * t + 1] = br; di[2 * t + 1] = bi;
  }
  transpose_r2c(dr, di, er, ei, fr, fi2, tile, lane, w);

  // P2: per col sigma_sv: inverse u-FFT (natural -> sigma_su), store Re / abs_eps.
  const float sc = 1.0f / 16384.0f;
#pragma unroll
  for (int ci = 0; ci < 8; ++ci) {
    int c = w * 8 + ci;
    float ar = er[ci], ai2 = ei[ci], br = fr[ci], bi = fi2[ci];
    fft128_dif<-1>(ar, ai2, br, bi, twr, twi, lane);
    if (isd) {
      optr[c * 128 + lane] = ar;
      optr[c * 128 + lane + 64] = br;
    } else {
      float t0r = ar * sc, t0i = ai2 * sc, t1r = br * sc, t1i = bi * sc;
      optr[c * 128 + lane] = sqrtf(t0r * t0r + t0i * t0i + 1e-6f);
      optr[c * 128 + lane + 64] = sqrtf(t1r * t1r + t1i * t1i + 1e-6f);
    }
  }
}

// [R6 body + R12 float4 loads] 256 blocks = (b,i)[64] x k-slice[4]; 512
// threads; register acc[33]; wave shfl-reduce -> LDS[8][33] -> 33 atomicAdds.
// Per thread: 2 iters x (1 xa float4 + 33 dfld float4) = 68 VMEM (was 272
// scalar); 264 FMAs unchanged. Same grid / reduction / decode as R6.
__global__ __launch_bounds__(512) void k_dot(const float* __restrict__ xa,
    const float* __restrict__ dfld, float* __restrict__ out) {
  int im = blockIdx.x >> 2;        // 0..63  (b*32+i)
  int slice = blockIdx.x & 3;
  int b = im >> 5, i = im & 31;
  int t = threadIdx.x;             // 0..511
  const float4* xr = (const float4*)(xa + im * 16384 + slice * 4096);
  const float4* db = (const float4*)(dfld + b * 33 * 16384 + slice * 4096);
  float acc[33];
#pragma unroll
  for (int j = 0; j < 33; ++j) acc[j] = 0.f;
#pragma unroll
  for (int it = 0; it < 2; ++it) {
    int k = it * 512 + t;          // float4 index, 1024 per slice
    float4 xv = xr[k];
#pragma unroll
    for (int j = 0; j < 33; ++j) {
      float4 dv = db[j * 4096 + k];
      acc[j] += xv.x * dv.x + xv.y * dv.y + xv.z * dv.z + xv.w * dv.w;
    }
  }
  // wave-level reduction per j
#pragma unroll
  for (int j = 0; j < 33; ++j) {
#pragma unroll
    for (int off = 32; off > 0; off >>= 1) acc[j] += __shfl_xor(acc[j], off, 64);
  }
  __shared__ float red[8][33];
  int w = t >> 6, lane = t & 63;
  if (lane == 0) {
#pragma unroll
    for (int j = 0; j < 33; ++j) red[w][j] = acc[j];
  }
  __syncthreads();
  if (t < 33) {
    float s = 0.f;
#pragma unroll
    for (int w2 = 0; w2 < 8; ++w2) s += red[w2][t];
    // decode output position for (i, j=t)
    int j = t;
    int j1 = i >> 3, l1 = i & 7;
    const int pref[4] = {0, 264, 464, 600};
    int per = (4 - j1) * 8 + 1;
    int start = pref[j1] + l1 * per;
    int pos = -1;
    if (j == 32) pos = start + per - 1;
    else {
      int j2 = j >> 3;
      if (j2 >= j1) pos = start + (j2 - j1) * 8 + (j & 7);
    }
    if (pos >= 0)
      atomicAdd(out + b * 672 + pos, s * (1.0f / 16384.0f) * (1.0f / 16384.0f));
  }
}

extern "C" void kernel_launch(void* const* d_in, const int* in_sizes, int n_in,
                              void* d_out, int out_size, void* d_ws, size_t ws_size,
                              hipStream_t stream) {
  (void)in_sizes; (void)n_in; (void)out_size; (void)ws_size;
  const float* x = (const float*)d_in[0];   // (2,1,128,128)
  const float* F = (const float*)d_in[1];   // (1,33,128,128)
  float* out = (float*)d_out;               // (2,672)
  char* ws = (char*)d_ws;
  // ws: X @0 (262144 B) | dfld @262144 (4325376 B) | xa @4587520 (4194304 B)
  float2* X = (float2*)(ws + 0);
  float* dfld = (float*)(ws + 262144);
  float* xa = (float*)(ws + 4587520);

  hipLaunchKernelGGL(k_prep, dim3(3), dim3(1024), 0, stream, x, X, out);
  hipLaunchKernelGGL(k_fields, dim3(130), dim3(1024), 0, stream, X, F, dfld, xa);
  hipLaunchKernelGGL(k_dot, dim3(256), dim3(512), 0, stream, xa, dfld, out);
}

// Round 3
// 106.106 us; speedup vs baseline: 1.1070x; 1.0718x over previous
//
#include <hip/hip_runtime.h>
#include <math.h>

// Third-order scattering via double-Parseval:
//   out[b,i,j] = (1/MN^2) * sum_n xa_{b,i}[n] * d_{b,j}[n]
// xa_i = abs_eps(inv2(F_i * X)/MN), d_j = Re(inv2_un(F_j^2 * X)), X = fft2(x).
// X in NATURAL frequency layout; inverse FFTs are conjugate-DIF (same DIF
// dataflow as forward, conjugated twiddles): natural freq input ->
// bit-reversed spatial output. All fields share the permutation, so the
// spatial dot products are unaffected.
//
// Hard-won constraints:
//  - R7: cooperative single-kernel fusion regressed 2.8x. Do not fuse.
//  - R8/R9: inverse FFT MUST be conjugate-DIF (span-64 stage FIRST, h=32..1,
//    forward-butterfly form, conjugated twiddles).
//  - R10: XCD-affine k_dot remap regressed; float4 alone (R12) is good.
//  - R11 FAILED: branchless fma-butterfly regressed (+2.9us). KEEP the
//    divergent if/else butterfly -- compiler if-conversion is optimal.
//  - R12 WIN: k_dot float4 loads (68 VMEM vs 272). 113.7us.
//  - R13 (this round): k_fields/k_prep are per-BLOCK-latency bound
//    (VALUBusy 10%, occupancy 20%, blocks < CUs). Two changes:
//    (a) Hermitian pairing: d_j = Re(ifft2(F_j^2 X)) = ifft2(G_j X) with
//        G_j(k) = (F_j^2(k)+F_j^2(-k))/2 real & symmetric (x real =>
//        conj(X(-k)) = X(k)). Pack two real-output fields per complex ifft:
//        ifft2((G_j + i G_j')X) = d_j + i d_j'.  66 d-FFTs -> 34.
//    (b) 2 blocks per field: duplicate P1 (8 fft calls), split P2 (4 calls).
//        12 vs 16 calls/block = 0.75x latency; 196 blocks fill the chip.
//
// 3 dispatches:
//  k_prep   : blocks 0-3: (b,half) X=fft2(x); block 4: zero out; 5-37: G_j.
//  k_fields : 196 blocks: 68 d-pair-half + 128 xa-half.
//  k_dot    : 256 blocks = (b,i) x 4 k-slices; float4, acc[33], shfl reduce.

#define PI_F 3.14159265358979323846f

__device__ __forceinline__ void make_tw(int lane, float* twr, float* twi) {
#pragma unroll
  for (int s = 0; s < 6; ++s) {
    int h = 32 >> s;
    float ang = -PI_F * (float)(lane & (h - 1)) / (float)h;
    float sv, cv;
    __sincosf(ang, &sv, &cv);
    twr[s] = cv; twi[s] = sv;
  }
  float ang = -PI_F * (float)lane / 64.0f;
  float sv, cv;
  __sincosf(ang, &sv, &cv);
  twr[6] = cv; twi[6] = sv;
}

// DIF radix-2: natural-order input (lane t holds x[t], x[t+64]); output slot s
// holds X[brev7(s)]. S=+1: forward (W^-); S=-1: inverse, unnormalized (W^+),
// SAME dataflow with conjugated twiddles (conjugate-DIF). [R6/R11-proven]
template <int S>
__device__ __forceinline__ void fft128_dif(float& ar, float& ai, float& br, float& bi,
                                           const float* twr, const float* twi, int lane) {
  float s6r = twr[6], s6i = (S > 0) ? twi[6] : -twi[6];
  float ur = ar + br, ui = ai + bi;
  float vr = ar - br, vi = ai - bi;
  ar = ur; ai = ui;
  br = vr * s6r - vi * s6i;
  bi = vr * s6i + vi * s6r;
#pragma unroll
  for (int s = 0; s < 6; ++s) {
    int h = 32 >> s;
    float wr = twr[s], wi = (S > 0) ? twi[s] : -twi[s];
    bool hi = (lane & h) != 0;
    float pr, pi2;
    pr = __shfl_xor(ar, h, 64); pi2 = __shfl_xor(ai, h, 64);
    if (!hi) { ar += pr; ai += pi2; }
    else { float dr = pr - ar, di = pi2 - ai; ar = dr * wr - di * wi; ai = dr * wi + di * wr; }
    pr = __shfl_xor(br, h, 64); pi2 = __shfl_xor(bi, h, 64);
    if (!hi) { br += pr; bi += pi2; }
    else { float dr = pr - br, di = pi2 - bi; br = dr * wr - di * wi; bi = dr * wi + di * wr; }
  }
}

// Write full 128x128 tile (two 64-row chunks), read back only 4 columns
// per chunk at colbase + w*4 + ci. XOR swizzle (c ^ (r&15)) conflict-free.
__device__ __forceinline__ void transpose_r2c_half(float (&dr)[16], float (&di)[16],
    float (&er)[4], float (&ei)[4], float (&fr)[4], float (&fi2)[4],
    float2 (*tile)[128], int lane, int w, int colbase) {
#pragma unroll
  for (int ch = 0; ch < 2; ++ch) {
    if ((w >> 3) == ch) {
#pragma unroll
      for (int t = 0; t < 8; ++t) {
        int r = w * 8 + t;
        int rr = r & 63, sw = r & 15;
        tile[rr][lane ^ sw] = make_float2(dr[2 * t], di[2 * t]);
        tile[rr][(lane + 64) ^ sw] = make_float2(dr[2 * t + 1], di[2 * t + 1]);
      }
    }
    __syncthreads();
    {
      int sw = lane & 15;
#pragma unroll
      for (int ci = 0; ci < 4; ++ci) {
        int c = colbase + w * 4 + ci;
        float2 v = tile[lane][c ^ sw];
        if (ch == 0) { er[ci] = v.x; ei[ci] = v.y; }
        else { fr[ci] = v.x; fi2[ci] = v.y; }
      }
    }
    __syncthreads();
  }
}

// blocks 0..3: (b,half): X[b] = fft2(x[b]) into NATURAL (u,v) layout, P2 split.
// block 4: zero out[1344].
// blocks 5..37: G_j(k) = 0.5*(F_j(k)^2 + F_j(-k)^2)  [Hermitian d-filter]
__global__ __launch_bounds__(1024, 2) void k_prep(const float* __restrict__ x,
    float2* __restrict__ X, float* __restrict__ out, const float* __restrict__ F,
    float* __restrict__ G) {
  __shared__ float2 tile[64][128];
  int tid = threadIdx.x;
  int bx = blockIdx.x;
  if (bx == 4) {
    if (tid < 1344) out[tid] = 0.f;
    return;
  }
  if (bx >= 5) {
    int j = bx - 5;
    const float* Fj = F + j * 16384;
    float* Gj = G + j * 16384;
    for (int k = tid; k < 16384; k += 1024) {
      int u = k >> 7, v = k & 127;
      int un = (128 - u) & 127, vn = (128 - v) & 127;
      float f = Fj[k], fn = Fj[un * 128 + vn];
      Gj[k] = 0.5f * (f * f + fn * fn);
    }
    return;
  }
  int b = bx >> 1, half = bx & 1;
  int lane = tid & 63, w = tid >> 6;
  float twr[7], twi[7]; make_tw(lane, twr, twi);
  const float* xb = x + b * 16384;
  float dr[16], di[16];
  float er[4], ei[4], fr[4], fi2[4];
#pragma unroll
  for (int t = 0; t < 8; ++t) {  // P1 (duplicated across halves): fwd v-FFT
    int r = w * 8 + t;
    float ar = xb[r * 128 + lane], ai2 = 0.f, br = xb[r * 128 + lane + 64], bi = 0.f;
    fft128_dif<1>(ar, ai2, br, bi, twr, twi, lane);
    dr[2 * t] = ar; di[2 * t] = ai2; dr[2 * t + 1] = br; di[2 * t + 1] = bi;
  }
  transpose_r2c_half(dr, di, er, ei, fr, fi2, tile, lane, w, half * 64);
  int u0 = __brev((unsigned)lane) >> 25;  // brev7(lane); brev7(lane+64)=u0+1
#pragma unroll
  for (int ci = 0; ci < 4; ++ci) {  // P2 half: fwd u-FFT, brev scatter-store
    int c = half * 64 + w * 4 + ci;
    float ar = er[ci], ai2 = ei[ci], br = fr[ci], bi = fi2[ci];
    fft128_dif<1>(ar, ai2, br, bi, twr, twi, lane);
    int vn = __brev((unsigned)c) >> 25;
    X[b * 16384 + u0 * 128 + vn] = make_float2(ar, ai2);
    X[b * 16384 + (u0 + 1) * 128 + vn] = make_float2(br, bi);
  }
}

// blocks 0..67:  d-pairs: (b x 17 pairs) x 2 halves.
//   pair p: j0=2p, j1=2p+1 (p<16); p==16 is the singleton j0=32.
//   Y = (G_j0 + i G_j1) * X; inv2_un(Y) = d_j0 + i d_j1 (both real fields).
// blocks 68..195: xa: (b*32+i) x 2 halves: xa = abs_eps(inv2_un(F_i X)/MN).
__global__ __launch_bounds__(1024, 2) void k_fields(const float2* __restrict__ X,
    const float* __restrict__ F, const float* __restrict__ G,
    float* __restrict__ dfld, float* __restrict__ xa) {
  __shared__ float2 tile[64][128];
  int tid = threadIdx.x, lane = tid & 63, w = tid >> 6;
  int bx = blockIdx.x;
  bool isd = (bx < 68);
  int b, half;
  bool has1 = false;
  const float* g0 = nullptr; const float* g1 = nullptr; const float* Fb = nullptr;
  float* o0; float* o1 = nullptr;
  if (isd) {
    int dp = bx >> 1; half = bx & 1;
    b = dp / 17; int p = dp - b * 17;
    int j0 = 2 * p; has1 = (p < 16);
    g0 = G + j0 * 16384;
    g1 = G + (j0 + 1) * 16384;
    o0 = dfld + (b * 33 + j0) * 16384;
    o1 = dfld + (b * 33 + j0 + 1) * 16384;
  } else {
    int q = bx - 68; int qi = q >> 1; half = q & 1;
    b = qi >> 5; int f = qi & 31;
    Fb = F + f * 16384;
    o0 = xa + qi * 16384;
  }
  float twr[7], twi[7]; make_tw(lane, twr, twi);
  const float2* Xb = X + b * 16384;
  float dr[16], di[16];
  float er[4], ei[4], fr[4], fi2[4];

  // P1 (duplicated across halves): Y = C * X, inverse v-FFT
#pragma unroll
  for (int t = 0; t < 8; ++t) {
    int r = w * 8 + t;
    float2 x0 = Xb[r * 128 + lane];
    float2 x1 = Xb[r * 128 + lane + 64];
    float ar, ai2, br, bi;
    if (isd) {
      float ga = g0[r * 128 + lane];
      float gb = has1 ? g1[r * 128 + lane] : 0.f;
      float gc = g0[r * 128 + lane + 64];
      float gd = has1 ? g1[r * 128 + lane + 64] : 0.f;
      ar = x0.x * ga - x0.y * gb; ai2 = x0.y * ga + x0.x * gb;
      br = x1.x * gc - x1.y * gd; bi = x1.y * gc + x1.x * gd;
    } else {
      float f0 = Fb[r * 128 + lane], f1 = Fb[r * 128 + lane + 64];
      ar = x0.x * f0; ai2 = x0.y * f0; br = x1.x * f1; bi = x1.y * f1;
    }
    fft128_dif<-1>(ar, ai2, br, bi, twr, twi, lane);
    dr[2 * t] = ar; di[2 * t] = ai2; dr[2 * t + 1] = br; di[2 * t + 1] = bi;
  }
  transpose_r2c_half(dr, di, er, ei, fr, fi2, tile, lane, w, half * 64);

  // P2 half: inverse u-FFT, store Re/Im (d-pair) or abs_eps (xa).
  const float sc = 1.0f / 16384.0f;
#pragma unroll
  for (int ci = 0; ci < 4; ++ci) {
    int c = half * 64 + w * 4 + ci;
    float ar = er[ci], ai2 = ei[ci], br = fr[ci], bi = fi2[ci];
    fft128_dif<-1>(ar, ai2, br, bi, twr, twi, lane);
    if (isd) {
      o0[c * 128 + lane] = ar;
      o0[c * 128 + lane + 64] = br;
      if (has1) {
        o1[c * 128 + lane] = ai2;
        o1[c * 128 + lane + 64] = bi;
      }
    } else {
      float t0r = ar * sc, t0i = ai2 * sc, t1r = br * sc, t1i = bi * sc;
      o0[c * 128 + lane] = sqrtf(t0r * t0r + t0i * t0i + 1e-6f);
      o0[c * 128 + lane + 64] = sqrtf(t1r * t1r + t1i * t1i + 1e-6f);
    }
  }
}

// [R6 body + R12 float4] 256 blocks = (b,i)[64] x k-slice[4]; 512 threads;
// register acc[33]; wave shfl-reduce -> LDS[8][33] -> 33 atomicAdds.
__global__ __launch_bounds__(512) void k_dot(const float* __restrict__ xa,
    const float* __restrict__ dfld, float* __restrict__ out) {
  int im = blockIdx.x >> 2;        // 0..63  (b*32+i)
  int slice = blockIdx.x & 3;
  int b = im >> 5, i = im & 31;
  int t = threadIdx.x;             // 0..511
  const float4* xr = (const float4*)(xa + im * 16384 + slice * 4096);
  const float4* db = (const float4*)(dfld + b * 33 * 16384 + slice * 4096);
  float acc[33];
#pragma unroll
  for (int j = 0; j < 33; ++j) acc[j] = 0.f;
#pragma unroll
  for (int it = 0; it < 2; ++it) {
    int k = it * 512 + t;          // float4 index, 1024 per slice
    float4 xv = xr[k];
#pragma unroll
    for (int j = 0; j < 33; ++j) {
      float4 dv = db[j * 4096 + k];
      acc[j] += xv.x * dv.x + xv.y * dv.y + xv.z * dv.z + xv.w * dv.w;
    }
  }
#pragma unroll
  for (int j = 0; j < 33; ++j) {
#pragma unroll
    for (int off = 32; off > 0; off >>= 1) acc[j] += __shfl_xor(acc[j], off, 64);
  }
  __shared__ float red[8][33];
  int w = t >> 6, lane = t & 63;
  if (lane == 0) {
#pragma unroll
    for (int j = 0; j < 33; ++j) red[w][j] = acc[j];
  }
  __syncthreads();
  if (t < 33) {
    float s = 0.f;
#pragma unroll
    for (int w2 = 0; w2 < 8; ++w2) s += red[w2][t];
    // decode output position for (i, j=t)
    int j = t;
    int j1 = i >> 3, l1 = i & 7;
    const int pref[4] = {0, 264, 464, 600};
    int per = (4 - j1) * 8 + 1;
    int start = pref[j1] + l1 * per;
    int pos = -1;
    if (j == 32) pos = start + per - 1;
    else {
      int j2 = j >> 3;
      if (j2 >= j1) pos = start + (j2 - j1) * 8 + (j & 7);
    }
    if (pos >= 0)
      atomicAdd(out + b * 672 + pos, s * (1.0f / 16384.0f) * (1.0f / 16384.0f));
  }
}

extern "C" void kernel_launch(void* const* d_in, const int* in_sizes, int n_in,
                              void* d_out, int out_size, void* d_ws, size_t ws_size,
                              hipStream_t stream) {
  (void)in_sizes; (void)n_in; (void)out_size; (void)ws_size;
  const float* x = (const float*)d_in[0];   // (2,1,128,128)
  const float* F = (const float*)d_in[1];   // (1,33,128,128)
  float* out = (float*)d_out;               // (2,672)
  char* ws = (char*)d_ws;
  // ws: X @0 (262144 B) | dfld @262144 (4325376 B) | xa @4587520 (4194304 B)
  //     | G @8781824 (2162688 B)
  float2* X = (float2*)(ws + 0);
  float* dfld = (float*)(ws + 262144);
  float* xa = (float*)(ws + 4587520);
  float* G = (float*)(ws + 8781824);

  hipLaunchKernelGGL(k_prep, dim3(38), dim3(1024), 0, stream, x, X, out, F, G);
  hipLaunchKernelGGL(k_fields, dim3(196), dim3(1024), 0, stream, X, F, G, dfld, xa);
  hipLaunchKernelGGL(k_dot, dim3(256), dim3(512), 0, stream, xa, dfld, out);
}

// Round 4
// 103.288 us; speedup vs baseline: 1.1372x; 1.0273x over previous
//
#include <hip/hip_runtime.h>
#include <math.h>

// Third-order scattering via double-Parseval:
//   out[b,i,j] = (1/MN^2) * sum_n xa_{b,i}[n] * d_{b,j}[n]
// xa_i = abs_eps(inv2(F_i * X)/MN), d_j = Re(inv2_un(F_j^2 * X)), X = fft2(x).
// X in NATURAL frequency layout; inverse FFTs are conjugate-DIF (same DIF
// dataflow as forward, conjugated twiddles): natural freq input ->
// bit-reversed spatial output. All fields share the permutation, so the
// spatial dot products are unaffected.
//
// Hard-won constraints:
//  - R7: cooperative single-kernel fusion regressed 2.8x. Do not fuse.
//  - R8/R9: inverse FFT MUST be conjugate-DIF (span-64 stage FIRST, h=32..1,
//    forward-butterfly form, conjugated twiddles).
//  - R10: XCD-affine k_dot remap regressed; float4 alone (R12) is good.
//  - R11 FAILED: branchless fma-butterfly regressed. KEEP the divergent
//    if/else butterfly -- compiler if-conversion is optimal.
//  - R12 WIN: k_dot float4 loads. 113.7us.
//  - R13 WIN: Hermitian d-pairing (66->34 d-FFTs) + 2-blocks-per-field
//    P2 split (12 vs 16 calls/block). 106.1us. Model: FFT blocks are
//    per-CU ISSUE-bound (VALU~DS balanced); keep blocks <= 256 CUs;
//    wall time ~ per-block issued instructions.
//  - R14 (this round): (a) k_dot j-split: 512 blocks = (b,i) x 4 slices x
//    2 j-halves, acc[17]; shfl-tree 198->102 DS ops/wave, 16 waves/CU.
//    (b) k_prep FFT x4 split: 8 blocks x 10 calls (chip is idle there).
//
// 3 dispatches:
//  k_prep   : blocks 0-7: (b,quarter) X=fft2(x); block 8: zero out; 9-41: G_j.
//  k_fields : 196 blocks: 68 d-pair-half + 128 xa-half.
//  k_dot    : 512 blocks = (b,i) x 4 k-slices x 2 j-halves.

#define PI_F 3.14159265358979323846f

__device__ __forceinline__ void make_tw(int lane, float* twr, float* twi) {
#pragma unroll
  for (int s = 0; s < 6; ++s) {
    int h = 32 >> s;
    float ang = -PI_F * (float)(lane & (h - 1)) / (float)h;
    float sv, cv;
    __sincosf(ang, &sv, &cv);
    twr[s] = cv; twi[s] = sv;
  }
  float ang = -PI_F * (float)lane / 64.0f;
  float sv, cv;
  __sincosf(ang, &sv, &cv);
  twr[6] = cv; twi[6] = sv;
}

// DIF radix-2: natural-order input (lane t holds x[t], x[t+64]); output slot s
// holds X[brev7(s)]. S=+1: forward (W^-); S=-1: inverse, unnormalized (W^+),
// SAME dataflow with conjugated twiddles (conjugate-DIF). [R6/R11-proven]
template <int S>
__device__ __forceinline__ void fft128_dif(float& ar, float& ai, float& br, float& bi,
                                           const float* twr, const float* twi, int lane) {
  float s6r = twr[6], s6i = (S > 0) ? twi[6] : -twi[6];
  float ur = ar + br, ui = ai + bi;
  float vr = ar - br, vi = ai - bi;
  ar = ur; ai = ui;
  br = vr * s6r - vi * s6i;
  bi = vr * s6i + vi * s6r;
#pragma unroll
  for (int s = 0; s < 6; ++s) {
    int h = 32 >> s;
    float wr = twr[s], wi = (S > 0) ? twi[s] : -twi[s];
    bool hi = (lane & h) != 0;
    float pr, pi2;
    pr = __shfl_xor(ar, h, 64); pi2 = __shfl_xor(ai, h, 64);
    if (!hi) { ar += pr; ai += pi2; }
    else { float dr = pr - ar, di = pi2 - ai; ar = dr * wr - di * wi; ai = dr * wi + di * wr; }
    pr = __shfl_xor(br, h, 64); pi2 = __shfl_xor(bi, h, 64);
    if (!hi) { br += pr; bi += pi2; }
    else { float dr = pr - br, di = pi2 - bi; br = dr * wr - di * wi; bi = dr * wi + di * wr; }
  }
}

// Write full 128x128 tile (two 64-row chunks), read back NC columns per wave
// per chunk at colbase + w*NC + ci. XOR swizzle (c ^ (r&15)) conflict-free.
template <int NC>
__device__ __forceinline__ void transpose_r2c_n(float (&dr)[16], float (&di)[16],
    float (&er)[NC], float (&ei)[NC], float (&fr)[NC], float (&fi2)[NC],
    float2 (*tile)[128], int lane, int w, int colbase) {
#pragma unroll
  for (int ch = 0; ch < 2; ++ch) {
    if ((w >> 3) == ch) {
#pragma unroll
      for (int t = 0; t < 8; ++t) {
        int r = w * 8 + t;
        int rr = r & 63, sw = r & 15;
        tile[rr][lane ^ sw] = make_float2(dr[2 * t], di[2 * t]);
        tile[rr][(lane + 64) ^ sw] = make_float2(dr[2 * t + 1], di[2 * t + 1]);
      }
    }
    __syncthreads();
    {
      int sw = lane & 15;
#pragma unroll
      for (int ci = 0; ci < NC; ++ci) {
        int c = colbase + w * NC + ci;
        float2 v = tile[lane][c ^ sw];
        if (ch == 0) { er[ci] = v.x; ei[ci] = v.y; }
        else { fr[ci] = v.x; fi2[ci] = v.y; }
      }
    }
    __syncthreads();
  }
}

// blocks 0..7: (b,quarter): X[b] = fft2(x[b]) NATURAL (u,v) layout, P2 1/4.
// block 8: zero out[1344].
// blocks 9..41: G_j(k) = 0.5*(F_j(k)^2 + F_j(-k)^2)  [Hermitian d-filter]
__global__ __launch_bounds__(1024, 2) void k_prep(const float* __restrict__ x,
    float2* __restrict__ X, float* __restrict__ out, const float* __restrict__ F,
    float* __restrict__ G) {
  __shared__ float2 tile[64][128];
  int tid = threadIdx.x;
  int bx = blockIdx.x;
  if (bx == 8) {
    if (tid < 1344) out[tid] = 0.f;
    return;
  }
  if (bx >= 9) {
    int j = bx - 9;
    const float* Fj = F + j * 16384;
    float* Gj = G + j * 16384;
    for (int k = tid; k < 16384; k += 1024) {
      int u = k >> 7, v = k & 127;
      int un = (128 - u) & 127, vn = (128 - v) & 127;
      float f = Fj[k], fn = Fj[un * 128 + vn];
      Gj[k] = 0.5f * (f * f + fn * fn);
    }
    return;
  }
  int b = bx >> 2, quarter = bx & 3;
  int lane = tid & 63, w = tid >> 6;
  float twr[7], twi[7]; make_tw(lane, twr, twi);
  const float* xb = x + b * 16384;
  float dr[16], di[16];
  float er[2], ei[2], fr[2], fi2[2];
#pragma unroll
  for (int t = 0; t < 8; ++t) {  // P1 (duplicated across quarters): fwd v-FFT
    int r = w * 8 + t;
    float ar = xb[r * 128 + lane], ai2 = 0.f, br = xb[r * 128 + lane + 64], bi = 0.f;
    fft128_dif<1>(ar, ai2, br, bi, twr, twi, lane);
    dr[2 * t] = ar; di[2 * t] = ai2; dr[2 * t + 1] = br; di[2 * t + 1] = bi;
  }
  transpose_r2c_n<2>(dr, di, er, ei, fr, fi2, tile, lane, w, quarter * 32);
  int u0 = __brev((unsigned)lane) >> 25;  // brev7(lane); brev7(lane+64)=u0+1
#pragma unroll
  for (int ci = 0; ci < 2; ++ci) {  // P2 quarter: fwd u-FFT, brev scatter
    int c = quarter * 32 + w * 2 + ci;
    float ar = er[ci], ai2 = ei[ci], br = fr[ci], bi = fi2[ci];
    fft128_dif<1>(ar, ai2, br, bi, twr, twi, lane);
    int vn = __brev((unsigned)c) >> 25;
    X[b * 16384 + u0 * 128 + vn] = make_float2(ar, ai2);
    X[b * 16384 + (u0 + 1) * 128 + vn] = make_float2(br, bi);
  }
}

// blocks 0..67:  d-pairs: (b x 17 pairs) x 2 halves.
//   pair p: j0=2p, j1=2p+1 (p<16); p==16 is the singleton j0=32.
//   Y = (G_j0 + i G_j1) * X; inv2_un(Y) = d_j0 + i d_j1 (both real fields).
// blocks 68..195: xa: (b*32+i) x 2 halves: xa = abs_eps(inv2_un(F_i X)/MN).
__global__ __launch_bounds__(1024, 2) void k_fields(const float2* __restrict__ X,
    const float* __restrict__ F, const float* __restrict__ G,
    float* __restrict__ dfld, float* __restrict__ xa) {
  __shared__ float2 tile[64][128];
  int tid = threadIdx.x, lane = tid & 63, w = tid >> 6;
  int bx = blockIdx.x;
  bool isd = (bx < 68);
  int b, half;
  bool has1 = false;
  const float* g0 = nullptr; const float* g1 = nullptr; const float* Fb = nullptr;
  float* o0; float* o1 = nullptr;
  if (isd) {
    int dp = bx >> 1; half = bx & 1;
    b = dp / 17; int p = dp - b * 17;
    int j0 = 2 * p; has1 = (p < 16);
    g0 = G + j0 * 16384;
    g1 = G + (j0 + 1) * 16384;
    o0 = dfld + (b * 33 + j0) * 16384;
    o1 = dfld + (b * 33 + j0 + 1) * 16384;
  } else {
    int q = bx - 68; int qi = q >> 1; half = q & 1;
    b = qi >> 5; int f = qi & 31;
    Fb = F + f * 16384;
    o0 = xa + qi * 16384;
  }
  float twr[7], twi[7]; make_tw(lane, twr, twi);
  const float2* Xb = X + b * 16384;
  float dr[16], di[16];
  float er[4], ei[4], fr[4], fi2[4];

  // P1 (duplicated across halves): Y = C * X, inverse v-FFT
#pragma unroll
  for (int t = 0; t < 8; ++t) {
    int r = w * 8 + t;
    float2 x0 = Xb[r * 128 + lane];
    float2 x1 = Xb[r * 128 + lane + 64];
    float ar, ai2, br, bi;
    if (isd) {
      float ga = g0[r * 128 + lane];
      float gb = has1 ? g1[r * 128 + lane] : 0.f;
      float gc = g0[r * 128 + lane + 64];
      float gd = has1 ? g1[r * 128 + lane + 64] : 0.f;
      ar = x0.x * ga - x0.y * gb; ai2 = x0.y * ga + x0.x * gb;
      br = x1.x * gc - x1.y * gd; bi = x1.y * gc + x1.x * gd;
    } else {
      float f0 = Fb[r * 128 + lane], f1 = Fb[r * 128 + lane + 64];
      ar = x0.x * f0; ai2 = x0.y * f0; br = x1.x * f1; bi = x1.y * f1;
    }
    fft128_dif<-1>(ar, ai2, br, bi, twr, twi, lane);
    dr[2 * t] = ar; di[2 * t] = ai2; dr[2 * t + 1] = br; di[2 * t + 1] = bi;
  }
  transpose_r2c_n<4>(dr, di, er, ei, fr, fi2, tile, lane, w, half * 64);

  // P2 half: inverse u-FFT, store Re/Im (d-pair) or abs_eps (xa).
  const float sc = 1.0f / 16384.0f;
#pragma unroll
  for (int ci = 0; ci < 4; ++ci) {
    int c = half * 64 + w * 4 + ci;
    float ar = er[ci], ai2 = ei[ci], br = fr[ci], bi = fi2[ci];
    fft128_dif<-1>(ar, ai2, br, bi, twr, twi, lane);
    if (isd) {
      o0[c * 128 + lane] = ar;
      o0[c * 128 + lane + 64] = br;
      if (has1) {
        o1[c * 128 + lane] = ai2;
        o1[c * 128 + lane + 64] = bi;
      }
    } else {
      float t0r = ar * sc, t0i = ai2 * sc, t1r = br * sc, t1i = bi * sc;
      o0[c * 128 + lane] = sqrtf(t0r * t0r + t0i * t0i + 1e-6f);
      o0[c * 128 + lane + 64] = sqrtf(t1r * t1r + t1i * t1i + 1e-6f);
    }
  }
}

// [R14] 512 blocks = (b,i)[64] x slice[4] x jhalf[2]; 512 threads; acc[17];
// shfl tree 102 DS ops (was 198); 2 blocks/CU => 16 waves/CU latency hiding.
// jhalf=0: j 0..16; jhalf=1: j 17..32 (17th lane idle at emit).
__global__ __launch_bounds__(512) void k_dot(const float* __restrict__ xa,
    const float* __restrict__ dfld, float* __restrict__ out) {
  int q = blockIdx.x;
  int im = q >> 3;                 // 0..63  (b*32+i)
  int slice = (q >> 1) & 3;        // 0..3
  int jh = q & 1;                  // 0..1
  int b = im >> 5, i = im & 31;
  int j0 = jh * 17;                // 0 or 17
  int t = threadIdx.x;             // 0..511
  const float4* xr = (const float4*)(xa + im * 16384 + slice * 4096);
  const float4* db = (const float4*)(dfld + (b * 33 + j0) * 16384 + slice * 4096);
  // jh=1,b=1: j index 16 would touch field 66 (one past dfld) -- that address
  // is still inside ws (xa region), loads are safe; result discarded at emit.
  float acc[17];
#pragma unroll
  for (int j = 0; j < 17; ++j) acc[j] = 0.f;
#pragma unroll
  for (int it = 0; it < 2; ++it) {
    int k = it * 512 + t;          // float4 index, 1024 per slice
    float4 xv = xr[k];
#pragma unroll
    for (int j = 0; j < 17; ++j) {
      float4 dv = db[j * 4096 + k];
      acc[j] += xv.x * dv.x + xv.y * dv.y + xv.z * dv.z + xv.w * dv.w;
    }
  }
#pragma unroll
  for (int j = 0; j < 17; ++j) {
#pragma unroll
    for (int off = 32; off > 0; off >>= 1) acc[j] += __shfl_xor(acc[j], off, 64);
  }
  __shared__ float red[8][17];
  int w = t >> 6, lane = t & 63;
  if (lane == 0) {
#pragma unroll
    for (int j = 0; j < 17; ++j) red[w][j] = acc[j];
  }
  __syncthreads();
  if (t < 17) {
    int j = j0 + t;                // global j 0..33
    float s = 0.f;
#pragma unroll
    for (int w2 = 0; w2 < 8; ++w2) s += red[w2][t];
    // decode output position for (i, j)
    int j1 = i >> 3, l1 = i & 7;
    const int pref[4] = {0, 264, 464, 600};
    int per = (4 - j1) * 8 + 1;
    int start = pref[j1] + l1 * per;
    int pos = -1;
    if (j == 32) pos = start + per - 1;
    else if (j < 32) {
      int j2 = j >> 3;
      if (j2 >= j1) pos = start + (j2 - j1) * 8 + (j & 7);
    }
    if (pos >= 0)
      atomicAdd(out + b * 672 + pos, s * (1.0f / 16384.0f) * (1.0f / 16384.0f));
  }
}

extern "C" void kernel_launch(void* const* d_in, const int* in_sizes, int n_in,
                              void* d_out, int out_size, void* d_ws, size_t ws_size,
                              hipStream_t stream) {
  (void)in_sizes; (void)n_in; (void)out_size; (void)ws_size;
  const float* x = (const float*)d_in[0];   // (2,1,128,128)
  const float* F = (const float*)d_in[1];   // (1,33,128,128)
  float* out = (float*)d_out;               // (2,672)
  char* ws = (char*)d_ws;
  // ws: X @0 (262144 B) | dfld @262144 (4325376 B) | xa @4587520 (4194304 B)
  //     | G @8781824 (2162688 B)
  float2* X = (float2*)(ws + 0);
  float* dfld = (float*)(ws + 262144);
  float* xa = (float*)(ws + 4587520);
  float* G = (float*)(ws + 8781824);

  hipLaunchKernelGGL(k_prep, dim3(42), dim3(1024), 0, stream, x, X, out, F, G);
  hipLaunchKernelGGL(k_fields, dim3(196), dim3(1024), 0, stream, X, F, G, dfld, xa);
  hipLaunchKernelGGL(k_dot, dim3(512), dim3(512), 0, stream, xa, dfld, out);
}